// Round 8
// baseline (533.369 us; speedup 1.0000x reference)
//
#include <hip/hip_runtime.h>
#include <stdint.h>

#define HID    1024
#define EXPERTS 8
#define TOPK   2
#define INNER  2048
#define NTOK   8192            // B*S
#define NPAIR  (NTOK * TOPK)   // 16384
#define MAXT   136             // max expert-pure 128-row tiles
#define BM 128
#define BN 256
#define BK 64
#define NSLOT 304              // 8 experts * 24 affinity slots + 112 overflow
#define AFFS  24

typedef _Float16 f16;
typedef f16   f16x8 __attribute__((ext_vector_type(8)));
typedef float f32x4 __attribute__((ext_vector_type(4)));

#define VMCNT(n) asm volatile("s_waitcnt vmcnt(" #n ")" ::: "memory")
#define BARRIER() do { __builtin_amdgcn_s_barrier(); asm volatile("" ::: "memory"); } while (0)

__device__ __forceinline__ void gload_lds16(const void* g, void* l) {
  __builtin_amdgcn_global_load_lds(
      (const __attribute__((address_space(1))) void*)g,
      (__attribute__((address_space(3))) void*)l, 16, 0, 0);
}

// =====================  router: logits, top-2, softmax (NO atomics)  ========
__global__ void router_kernel(const float* __restrict__ x,
                              const float* __restrict__ Wr,
                              const float* __restrict__ br,
                              int* __restrict__ e_sel, float* __restrict__ w_sel) {
  int gid  = blockIdx.x * blockDim.x + threadIdx.x;
  int wid  = gid >> 6;
  int lane = gid & 63;
  if (wid >= NTOK) return;

  const f32x4* xr = (const f32x4*)(x + (size_t)wid * HID);
  float acc[EXPERTS];
#pragma unroll
  for (int e = 0; e < EXPERTS; ++e) acc[e] = 0.f;
#pragma unroll
  for (int j = 0; j < HID / 256; ++j) {
    f32x4 xv = xr[j * 64 + lane];
    int   k  = (j * 64 + lane) * 4;
    const float* wr = Wr + (size_t)k * EXPERTS;
#pragma unroll
    for (int r = 0; r < 4; ++r) {
      float xs = xv[r];
      f32x4 w0 = *(const f32x4*)(wr + r * 8);
      f32x4 w1 = *(const f32x4*)(wr + r * 8 + 4);
#pragma unroll
      for (int e = 0; e < 4; ++e) { acc[e] += xs * w0[e]; acc[4 + e] += xs * w1[e]; }
    }
  }
#pragma unroll
  for (int e = 0; e < EXPERTS; ++e) {
#pragma unroll
    for (int off = 32; off > 0; off >>= 1) acc[e] += __shfl_xor(acc[e], off);
  }
  if (lane == 0) {
    float lg[EXPERTS];
#pragma unroll
    for (int e = 0; e < EXPERTS; ++e) lg[e] = acc[e] + br[e];
    int e0 = 0; float l0 = lg[0];
#pragma unroll
    for (int e = 1; e < EXPERTS; ++e) if (lg[e] > l0) { l0 = lg[e]; e0 = e; }
    int e1 = -1; float l1 = -3.4e38f;
#pragma unroll
    for (int e = 0; e < EXPERTS; ++e) if (e != e0 && lg[e] > l1) { l1 = lg[e]; e1 = e; }
    float a  = __expf(l1 - l0);
    float w0 = 1.f / (1.f + a);
    float w1 = a * w0;
    e_sel[wid * 2]     = e0;  e_sel[wid * 2 + 1] = e1;
    w_sel[wid * 2]     = w0;  w_sel[wid * 2 + 1] = w1;
  }
}

// ====  dispatch: counts + scan + slot map (XCD affinity) + scatter  =========
__global__ __launch_bounds__(1024) void dispatch_kernel(
    const int* __restrict__ e_sel, const float* __restrict__ w_sel,
    int* __restrict__ tok_list, float* __restrict__ wt_list,
    int* __restrict__ counts, int* __restrict__ bases,
    int* __restrict__ slot_e, int* __restrict__ slot_m0,
    int* __restrict__ slot_g, int* __restrict__ tinfo) {
  __shared__ int scnt[EXPERTS][1024];
  __shared__ int etot[EXPERTS];
  __shared__ int ebase[EXPERTS];
  int tid = threadIdx.x, lane = tid & 63, wv = tid >> 6;

  int myE[16]; float myW[16];
  int lc[EXPERTS];
#pragma unroll
  for (int e = 0; e < EXPERTS; ++e) lc[e] = 0;
#pragma unroll
  for (int i = 0; i < 16; ++i) {
    int p = tid * 16 + i;
    myE[i] = e_sel[p];
    myW[i] = w_sel[p];
#pragma unroll
    for (int e = 0; e < EXPERTS; ++e) lc[e] += (myE[i] == e);
  }
#pragma unroll
  for (int e = 0; e < EXPERTS; ++e) scnt[e][tid] = lc[e];
  __syncthreads();

  if (wv < EXPERTS) {
    int run = 0;
    for (int c = 0; c < 16; ++c) {
      int v = scnt[wv][c * 64 + lane];
      int incl = v;
#pragma unroll
      for (int off = 1; off < 64; off <<= 1) {
        int n = __shfl_up(incl, off);
        if (lane >= off) incl += n;
      }
      scnt[wv][c * 64 + lane] = run + incl - v;
      run += __shfl(incl, 63);
    }
    if (lane == 0) etot[wv] = run;
  }
  __syncthreads();

  if (tid < NSLOT) slot_e[tid] = -1;
  __syncthreads();
  if (tid == 0) {
    int s = 0;
    for (int e = 0; e < EXPERTS; ++e) {
      ebase[e] = s; bases[e] = s; counts[e] = etot[e]; s += etot[e];
    }
    int ov = AFFS * EXPERTS, gt = 0;
    for (int e = 0; e < EXPERTS; ++e) {
      int ntl = (etot[e] + BM - 1) / BM;
      for (int i = 0; i < ntl; ++i) {
        int sl = (i < AFFS) ? (e + EXPERTS * i) : (ov++);
        slot_e[sl] = e; slot_m0[sl] = i * BM; slot_g[sl] = gt++;
      }
    }
    tinfo[0] = gt;
  }
  __syncthreads();

  int cur[EXPERTS];
#pragma unroll
  for (int e = 0; e < EXPERTS; ++e) cur[e] = ebase[e] + scnt[e][tid];
#pragma unroll
  for (int i = 0; i < 16; ++i) {
    int p = 0;
#pragma unroll
    for (int e = 0; e < EXPERTS; ++e) if (myE[i] == e) p = cur[e]++;
    tok_list[p] = (tid * 16 + i) >> 1;
    wt_list[p]  = myW[i];
  }
}

// =====================  pre-pass: fp32 -> fp16 (+transpose)  ================
__global__ void convert_x_kernel(const float* __restrict__ x,
                                 f16* __restrict__ x16, int n8) {
  int i = blockIdx.x * blockDim.x + threadIdx.x;
  int stride = gridDim.x * blockDim.x;
  for (; i < n8; i += stride) {
    f32x4 a = ((const f32x4*)x)[i * 2];
    f32x4 b = ((const f32x4*)x)[i * 2 + 1];
    f16x8 o;
#pragma unroll
    for (int j = 0; j < 4; ++j) { o[j] = (f16)a[j]; o[4 + j] = (f16)b[j]; }
    ((f16x8*)x16)[i] = o;
  }
}

__global__ void transpose_cvt_kernel(const float* __restrict__ src,
                                     f16* __restrict__ dst, int R, int C) {
  __shared__ float tile[32][33];
  int z = blockIdx.z;
  src += (size_t)z * R * C;
  dst += (size_t)z * R * C;
  int c0 = blockIdx.x * 32, r0 = blockIdx.y * 32;
  int tx = threadIdx.x, ty = threadIdx.y;
#pragma unroll
  for (int i = 0; i < 4; ++i)
    tile[ty + i * 8][tx] = src[(size_t)(r0 + ty + i * 8) * C + c0 + tx];
  __syncthreads();
#pragma unroll
  for (int i = 0; i < 4; ++i)
    dst[(size_t)(c0 + ty + i * 8) * R + r0 + tx] = (f16)tile[tx][ty + i * 8];
}

// ============================================================================
// GEMM core: 128x256 tile, BK=64, 8 waves (2x4 of 64x64), depth-3 counted
// pipeline.  LDS buffer = A[128x64] (16KB) + B[256x64] (32KB) = 48KB, x3.
// Stored chunk (row,c) holds global chunk (row, c^(row&7)) via pre-swizzled
// GLOBAL source (gload_lds dest linear).  Per stage: 6 gload_lds / thread.
// Counted vmcnt(6) keeps 2 stages in flight across raw s_barriers.
// ============================================================================

#define STAGE6(BUF) do {                                                      \
  _Pragma("unroll") for (int i_ = 0; i_ < 2; ++i_) {                          \
    gload_lds16(gA[i_], (BUF) + i_ * 4096 + wid * 512); gA[i_] += BK;         \
  }                                                                           \
  _Pragma("unroll") for (int i_ = 0; i_ < 4; ++i_) {                          \
    gload_lds16(gB[i_], (BUF) + 8192 + i_ * 4096 + wid * 512); gB[i_] += BK;  \
  }                                                                           \
} while (0)

#define COMPUTE16(BUF) do {                                                   \
  _Pragma("unroll") for (int kk_ = 0; kk_ < 2; ++kk_) {                       \
    int lc_ = (kk_ * 4 + hi) ^ sa;                                            \
    f16x8 af_[4], bf_[4];                                                     \
    _Pragma("unroll") for (int mi_ = 0; mi_ < 4; ++mi_)                       \
      af_[mi_] = *(const f16x8*)((BUF) + (wm + mi_ * 16 + ar) * 64 + lc_ * 8);\
    _Pragma("unroll") for (int ni_ = 0; ni_ < 4; ++ni_)                       \
      bf_[ni_] = *(const f16x8*)((BUF) + 8192 +                               \
                                 (wn + ni_ * 16 + ar) * 64 + lc_ * 8);        \
    _Pragma("unroll") for (int mi_ = 0; mi_ < 4; ++mi_)                       \
      _Pragma("unroll") for (int ni_ = 0; ni_ < 4; ++ni_)                     \
        acc[mi_][ni_] = __builtin_amdgcn_mfma_f32_16x16x32_f16(               \
            af_[mi_], bf_[ni_], acc[mi_][ni_], 0, 0, 0);                      \
  }                                                                           \
} while (0)

#define PIPELINE_LOOP(NT) do {                                                \
  STAGE6(q0); STAGE6(q1);                                                     \
  VMCNT(6); BARRIER();                                                        \
  for (int t = 0; t < (NT); ++t) {                                            \
    if (t + 2 < (NT)) { STAGE6(q2); }                                         \
    COMPUTE16(q0);                                                            \
    if (t + 2 < (NT)) { VMCNT(6); } else { VMCNT(0); }                        \
    BARRIER();                                                                \
    f16* tm_ = q0; q0 = q1; q1 = q2; q2 = tm_;                                \
  }                                                                           \
} while (0)

// =====================  GEMM1: h = relu(x @ W1 + b1)  =======================
__global__ __launch_bounds__(512, 2) void gemm1_kernel(
    const f16* __restrict__ x16, const f16* __restrict__ w1t,
    const float* __restrict__ bias1, const int* __restrict__ tok_list,
    const int* __restrict__ counts, const int* __restrict__ bases,
    const int* __restrict__ slot_e, const int* __restrict__ slot_m0,
    const int* __restrict__ slot_g, int c0, int G,
    f16* __restrict__ h16) {
  int sx = blockIdx.x;
  int e  = slot_e[sx];
  if (e < 0) return;
  int g  = slot_g[sx];
  if (g < c0 || g >= c0 + G) return;
  int m0 = slot_m0[sx];
  int cnt = counts[e], base = bases[e];
  int n0 = blockIdx.y * BN;
  const f16* Bg = w1t + (size_t)e * INNER * HID;

  __shared__ __align__(16) f16 LDS[3 * 24576];
  f16 *q0 = LDS, *q1 = LDS + 24576, *q2 = LDS + 2 * 24576;

  int tid = threadIdx.x, lane = tid & 63, wid = tid >> 6;
  int wm = (wid >> 2) * 64, wn = (wid & 3) * 64;
  int ar = lane & 15, hi = lane >> 4, sa = ar & 7;

  int trow = tid >> 3;
  int gcol = (tid & 7) ^ (trow & 7);
  const f16* gA[2];
  const f16* gB[4];
#pragma unroll
  for (int i = 0; i < 2; ++i) {
    int row = i * 64 + trow;
    int tok = tok_list[base + min(m0 + row, cnt - 1)];
    gA[i] = x16 + (size_t)tok * HID + gcol * 8;
  }
#pragma unroll
  for (int i = 0; i < 4; ++i) {
    int row = i * 64 + trow;
    gB[i] = Bg + (size_t)(n0 + row) * HID + gcol * 8;
  }

  f32x4 acc[4][4];
#pragma unroll
  for (int i = 0; i < 4; ++i)
#pragma unroll
    for (int j = 0; j < 4; ++j) acc[i][j] = (f32x4){0.f, 0.f, 0.f, 0.f};

  PIPELINE_LOOP(HID / BK);   // 16

  int colc = ar, rbase = hi * 4;
  float bb[4];
#pragma unroll
  for (int ni = 0; ni < 4; ++ni)
    bb[ni] = bias1[(size_t)e * INNER + n0 + wn + ni * 16 + colc];
#pragma unroll
  for (int mi = 0; mi < 4; ++mi)
#pragma unroll
    for (int r = 0; r < 4; ++r) {
      int ml = wm + mi * 16 + rbase + r;
      if (m0 + ml < cnt) {
        size_t rowoff = (size_t)((g - c0) * BM + ml) * INNER + n0 + wn + colc;
#pragma unroll
        for (int ni = 0; ni < 4; ++ni) {
          float v = acc[mi][ni][r] + bb[ni];
          h16[rowoff + ni * 16] = (f16)fmaxf(v, 0.f);
        }
      }
    }
}

// =====================  GEMM2: out += w * (h @ W2 + b2), K-split=2  =========
__global__ __launch_bounds__(512, 2) void gemm2_kernel(
    const f16* __restrict__ h16, const f16* __restrict__ w2t,
    const float* __restrict__ bias2, const int* __restrict__ tok_list,
    const float* __restrict__ wt_list, const int* __restrict__ counts,
    const int* __restrict__ bases,
    const int* __restrict__ slot_e, const int* __restrict__ slot_m0,
    const int* __restrict__ slot_g, int c0, int G,
    float* __restrict__ out) {
  int sx = blockIdx.x;
  int e  = slot_e[sx];
  if (e < 0) return;
  int g  = slot_g[sx];
  if (g < c0 || g >= c0 + G) return;
  int m0 = slot_m0[sx];
  int cnt = counts[e], base = bases[e];
  int d0 = blockIdx.y * BN;
  int kc = blockIdx.z;
  int koff = kc * (INNER / 2);
  const f16* Bg = w2t + (size_t)e * HID * INNER;

  __shared__ __align__(16) f16 LDS[3 * 24576];
  f16 *q0 = LDS, *q1 = LDS + 24576, *q2 = LDS + 2 * 24576;

  int tid = threadIdx.x, lane = tid & 63, wid = tid >> 6;
  int wm = (wid >> 2) * 64, wn = (wid & 3) * 64;
  int ar = lane & 15, hi = lane >> 4, sa = ar & 7;

  int trow = tid >> 3;
  int gcol = (tid & 7) ^ (trow & 7);
  const f16* gA[2];
  const f16* gB[4];
#pragma unroll
  for (int i = 0; i < 2; ++i) {
    int row  = i * 64 + trow;
    int lrow = min(m0 + row, cnt - 1) - m0;
    gA[i] = h16 + ((size_t)(g - c0) * BM + lrow) * INNER + koff + gcol * 8;
  }
#pragma unroll
  for (int i = 0; i < 4; ++i) {
    int row = i * 64 + trow;
    gB[i] = Bg + (size_t)(d0 + row) * INNER + koff + gcol * 8;
  }

  f32x4 acc[4][4];
#pragma unroll
  for (int i = 0; i < 4; ++i)
#pragma unroll
    for (int j = 0; j < 4; ++j) acc[i][j] = (f32x4){0.f, 0.f, 0.f, 0.f};

  PIPELINE_LOOP((INNER / 2) / BK);   // 16

  int colc = ar, rbase = hi * 4;
  float bb[4];
#pragma unroll
  for (int ni = 0; ni < 4; ++ni)
    bb[ni] = (kc == 0) ? bias2[(size_t)e * HID + d0 + wn + ni * 16 + colc] : 0.f;
#pragma unroll
  for (int mi = 0; mi < 4; ++mi)
#pragma unroll
    for (int r = 0; r < 4; ++r) {
      int ml = wm + mi * 16 + rbase + r;
      if (m0 + ml < cnt) {
        int   p   = base + m0 + ml;
        int   tok = tok_list[p];
        float w   = wt_list[p];
        float* orow = out + (size_t)tok * HID + d0 + wn + colc;
#pragma unroll
        for (int ni = 0; ni < 4; ++ni) {
          float v = acc[mi][ni][r] + bb[ni];
          atomicAdd(orow + ni * 16, v * w);
        }
      }
    }
}

// ===========================================================================
extern "C" void kernel_launch(void* const* d_in, const int* in_sizes, int n_in,
                              void* d_out, int out_size, void* d_ws, size_t ws_size,
                              hipStream_t stream) {
  (void)in_sizes; (void)n_in;
  const float* x  = (const float*)d_in[0];
  const float* Wr = (const float*)d_in[1];
  const float* br = (const float*)d_in[2];
  const float* W1 = (const float*)d_in[3];
  const float* b1 = (const float*)d_in[4];
  const float* W2 = (const float*)d_in[5];
  const float* b2 = (const float*)d_in[6];
  float* out = (float*)d_out;

  char*  ws  = (char*)d_ws;
  size_t off = 0;
  auto alloc = [&](size_t bytes) {
    char* p = ws + off;
    off += bytes; off = (off + 255) & ~(size_t)255;
    return p;
  };
  int*   tok_list = (int*)alloc(NPAIR * sizeof(int));
  float* wt_list  = (float*)alloc(NPAIR * sizeof(float));
  int*   e_sel    = (int*)alloc(NTOK * 2 * sizeof(int));
  float* w_sel    = (float*)alloc(NTOK * 2 * sizeof(float));
  int*   counts   = (int*)alloc(EXPERTS * sizeof(int));
  int*   bases    = (int*)alloc(EXPERTS * sizeof(int));
  int*   slot_e   = (int*)alloc(NSLOT * sizeof(int));
  int*   slot_m0  = (int*)alloc(NSLOT * sizeof(int));
  int*   slot_g   = (int*)alloc(NSLOT * sizeof(int));
  int*   tinfo    = (int*)alloc(16 * sizeof(int));
  f16*   w1t      = (f16*)alloc((size_t)EXPERTS * HID * INNER * sizeof(f16));
  f16*   w2t      = (f16*)alloc((size_t)EXPERTS * HID * INNER * sizeof(f16));
  f16*   x16      = (f16*)alloc((size_t)NTOK * HID * sizeof(f16));
  const size_t TILE_BYTES = (size_t)BM * INNER * sizeof(f16);  // 512 KB
  size_t rem = (ws_size > off) ? (ws_size - off) : 0;
  int G = (int)(rem / TILE_BYTES);
  if (G < 1) G = 1;
  if (G > MAXT) G = MAXT;
  int nch = (MAXT + G - 1) / G;
  f16* h16 = (f16*)(ws + off);

  hipMemsetAsync(out, 0, (size_t)out_size * sizeof(float), stream);

  convert_x_kernel<<<2048, 256, 0, stream>>>(x, x16, NTOK * HID / 8);
  transpose_cvt_kernel<<<dim3(INNER / 32, HID / 32, EXPERTS), dim3(32, 8), 0, stream>>>(
      W1, w1t, HID, INNER);
  transpose_cvt_kernel<<<dim3(HID / 32, INNER / 32, EXPERTS), dim3(32, 8), 0, stream>>>(
      W2, w2t, INNER, HID);
  router_kernel<<<NTOK / 4, 256, 0, stream>>>(x, Wr, br, e_sel, w_sel);
  dispatch_kernel<<<1, 1024, 0, stream>>>(e_sel, w_sel, tok_list, wt_list,
                                          counts, bases, slot_e, slot_m0, slot_g, tinfo);

  for (int c = 0; c < nch; ++c) {
    int c0 = c * G;
    gemm1_kernel<<<dim3(NSLOT, INNER / BN, 1), 512, 0, stream>>>(
        x16, w1t, b1, tok_list, counts, bases, slot_e, slot_m0, slot_g, c0, G, h16);
    gemm2_kernel<<<dim3(NSLOT, HID / BN, 2), 512, 0, stream>>>(
        h16, w2t, b2, tok_list, wt_list, counts, bases, slot_e, slot_m0, slot_g, c0, G, out);
  }
}

// Round 10
// 502.700 us; speedup vs baseline: 1.0610x; 1.0610x over previous
//
#include <hip/hip_runtime.h>
#include <stdint.h>

#define HID    1024
#define EXPERTS 8
#define TOPK   2
#define INNER  2048
#define NTOK   8192            // B*S
#define NPAIR  (NTOK * TOPK)   // 16384
#define MAXT   136             // max expert-pure 128-row tiles
#define BM 128
#define BN 128
#define BK 32
#define AFFS  17               // affinity slots per expert (8*17 = 136 = MAXT)
#define NSLOT 200              // 136 affinity + 64 overflow

typedef _Float16 f16;
typedef f16   f16x8 __attribute__((ext_vector_type(8)));
typedef float f32x4 __attribute__((ext_vector_type(4)));

#define VMCNT(n) asm volatile("s_waitcnt vmcnt(" #n ")" ::: "memory")
#define BARRIER() do { __builtin_amdgcn_s_barrier(); asm volatile("" ::: "memory"); } while (0)

__device__ __forceinline__ void gload_lds16(const void* g, void* l) {
  __builtin_amdgcn_global_load_lds(
      (const __attribute__((address_space(1))) void*)g,
      (__attribute__((address_space(3))) void*)l, 16, 0, 0);
}

// =====================  router: logits, top-2, softmax (NO atomics)  ========
__global__ void router_kernel(const float* __restrict__ x,
                              const float* __restrict__ Wr,
                              const float* __restrict__ br,
                              int* __restrict__ e_sel, float* __restrict__ w_sel) {
  int gid  = blockIdx.x * blockDim.x + threadIdx.x;
  int wid  = gid >> 6;
  int lane = gid & 63;
  if (wid >= NTOK) return;

  const f32x4* xr = (const f32x4*)(x + (size_t)wid * HID);
  float acc[EXPERTS];
#pragma unroll
  for (int e = 0; e < EXPERTS; ++e) acc[e] = 0.f;
#pragma unroll
  for (int j = 0; j < HID / 256; ++j) {
    f32x4 xv = xr[j * 64 + lane];
    int   k  = (j * 64 + lane) * 4;
    const float* wr = Wr + (size_t)k * EXPERTS;
#pragma unroll
    for (int r = 0; r < 4; ++r) {
      float xs = xv[r];
      f32x4 w0 = *(const f32x4*)(wr + r * 8);
      f32x4 w1 = *(const f32x4*)(wr + r * 8 + 4);
#pragma unroll
      for (int e = 0; e < 4; ++e) { acc[e] += xs * w0[e]; acc[4 + e] += xs * w1[e]; }
    }
  }
#pragma unroll
  for (int e = 0; e < EXPERTS; ++e) {
#pragma unroll
    for (int off = 32; off > 0; off >>= 1) acc[e] += __shfl_xor(acc[e], off);
  }
  if (lane == 0) {
    float lg[EXPERTS];
#pragma unroll
    for (int e = 0; e < EXPERTS; ++e) lg[e] = acc[e] + br[e];
    int e0 = 0; float l0 = lg[0];
#pragma unroll
    for (int e = 1; e < EXPERTS; ++e) if (lg[e] > l0) { l0 = lg[e]; e0 = e; }
    int e1 = -1; float l1 = -3.4e38f;
#pragma unroll
    for (int e = 0; e < EXPERTS; ++e) if (e != e0 && lg[e] > l1) { l1 = lg[e]; e1 = e; }
    float a  = __expf(l1 - l0);
    float w0 = 1.f / (1.f + a);
    float w1 = a * w0;
    e_sel[wid * 2]     = e0;  e_sel[wid * 2 + 1] = e1;
    w_sel[wid * 2]     = w0;  w_sel[wid * 2 + 1] = w1;
  }
}

// ====  dispatch: counts + scan + slot map (XCD affinity) + scatter  =========
__global__ __launch_bounds__(1024) void dispatch_kernel(
    const int* __restrict__ e_sel, const float* __restrict__ w_sel,
    int* __restrict__ tok_list, float* __restrict__ wt_list,
    int* __restrict__ counts, int* __restrict__ bases,
    int* __restrict__ slot_e, int* __restrict__ slot_m0,
    int* __restrict__ slot_g, int* __restrict__ tinfo) {
  __shared__ int scnt[EXPERTS][1024];
  __shared__ int etot[EXPERTS];
  __shared__ int ebase[EXPERTS];
  int tid = threadIdx.x, lane = tid & 63, wv = tid >> 6;

  int myE[16]; float myW[16];
  int lc[EXPERTS];
#pragma unroll
  for (int e = 0; e < EXPERTS; ++e) lc[e] = 0;
#pragma unroll
  for (int i = 0; i < 16; ++i) {
    int p = tid * 16 + i;
    myE[i] = e_sel[p];
    myW[i] = w_sel[p];
#pragma unroll
    for (int e = 0; e < EXPERTS; ++e) lc[e] += (myE[i] == e);
  }
#pragma unroll
  for (int e = 0; e < EXPERTS; ++e) scnt[e][tid] = lc[e];
  __syncthreads();

  if (wv < EXPERTS) {
    int run = 0;
    for (int c = 0; c < 16; ++c) {
      int v = scnt[wv][c * 64 + lane];
      int incl = v;
#pragma unroll
      for (int off = 1; off < 64; off <<= 1) {
        int n = __shfl_up(incl, off);
        if (lane >= off) incl += n;
      }
      scnt[wv][c * 64 + lane] = run + incl - v;
      run += __shfl(incl, 63);
    }
    if (lane == 0) etot[wv] = run;
  }
  __syncthreads();

  if (tid < NSLOT) slot_e[tid] = -1;
  __syncthreads();
  if (tid == 0) {
    int s = 0;
    for (int e = 0; e < EXPERTS; ++e) {
      ebase[e] = s; bases[e] = s; counts[e] = etot[e]; s += etot[e];
    }
    int ov = AFFS * EXPERTS, gt = 0;
    for (int e = 0; e < EXPERTS; ++e) {
      int ntl = (etot[e] + BM - 1) / BM;
      for (int i = 0; i < ntl; ++i) {
        int sl = (i < AFFS) ? (e + EXPERTS * i) : (ov++);
        slot_e[sl] = e; slot_m0[sl] = i * BM; slot_g[sl] = gt++;
      }
    }
    tinfo[0] = gt;
  }
  __syncthreads();

  int cur[EXPERTS];
#pragma unroll
  for (int e = 0; e < EXPERTS; ++e) cur[e] = ebase[e] + scnt[e][tid];
#pragma unroll
  for (int i = 0; i < 16; ++i) {
    int p = 0;
#pragma unroll
    for (int e = 0; e < EXPERTS; ++e) if (myE[i] == e) p = cur[e]++;
    tok_list[p] = (tid * 16 + i) >> 1;
    wt_list[p]  = myW[i];
  }
}

// =====================  pre-pass: fp32 -> fp16 (+transpose)  ================
__global__ void convert_x_kernel(const float* __restrict__ x,
                                 f16* __restrict__ x16, int n8) {
  int i = blockIdx.x * blockDim.x + threadIdx.x;
  int stride = gridDim.x * blockDim.x;
  for (; i < n8; i += stride) {
    f32x4 a = ((const f32x4*)x)[i * 2];
    f32x4 b = ((const f32x4*)x)[i * 2 + 1];
    f16x8 o;
#pragma unroll
    for (int j = 0; j < 4; ++j) { o[j] = (f16)a[j]; o[4 + j] = (f16)b[j]; }
    ((f16x8*)x16)[i] = o;
  }
}

__global__ void transpose_cvt_kernel(const float* __restrict__ src,
                                     f16* __restrict__ dst, int R, int C) {
  __shared__ float tile[32][33];
  int z = blockIdx.z;
  src += (size_t)z * R * C;
  dst += (size_t)z * R * C;
  int c0 = blockIdx.x * 32, r0 = blockIdx.y * 32;
  int tx = threadIdx.x, ty = threadIdx.y;
#pragma unroll
  for (int i = 0; i < 4; ++i)
    tile[ty + i * 8][tx] = src[(size_t)(r0 + ty + i * 8) * C + c0 + tx];
  __syncthreads();
#pragma unroll
  for (int i = 0; i < 4; ++i)
    dst[(size_t)(c0 + ty + i * 8) * R + r0 + tx] = (f16)tile[tx][ty + i * 8];
}

// ============================================================================
// GEMM core: 128x128 tile, BK=32, 4 waves (2x2 of 64x64), depth-2-in-flight
// counted pipeline over 3 LDS buffers (16KB each, 48KB total -> 3 blocks/CU,
// 12 waves/CU).  LDS rows are 64B (4 chunks of 16B); stored chunk (row,c)
// holds global chunk (row, c^((row>>1)&3)) via pre-swizzled GLOBAL source
// (gload_lds dest linear).  Fragment reads XOR the same pattern -> 2-way
// bank spread (free).  Per stage: 4 gload_lds / thread; vmcnt(4) keeps one
// extra stage in flight across the single per-step barrier.
// ============================================================================

#define STAGE4(BUF) do {                                                      \
  _Pragma("unroll") for (int i_ = 0; i_ < 2; ++i_) {                          \
    gload_lds16(gA[i_], (BUF) + i_ * 2048 + wid * 512); gA[i_] += BK;         \
    gload_lds16(gB[i_], (BUF) + 4096 + i_ * 2048 + wid * 512); gB[i_] += BK;  \
  }                                                                           \
} while (0)

#define COMPUTE8(BUF) do {                                                    \
  f16x8 af_[4], bf_[4];                                                       \
  _Pragma("unroll") for (int mi_ = 0; mi_ < 4; ++mi_)                         \
    af_[mi_] = *(const f16x8*)((BUF) + (wm + mi_ * 16 + ar) * 32 + cswz * 8); \
  _Pragma("unroll") for (int ni_ = 0; ni_ < 4; ++ni_)                         \
    bf_[ni_] = *(const f16x8*)((BUF) + 4096 +                                 \
                               (wn + ni_ * 16 + ar) * 32 + cswz * 8);         \
  _Pragma("unroll") for (int mi_ = 0; mi_ < 4; ++mi_)                         \
    _Pragma("unroll") for (int ni_ = 0; ni_ < 4; ++ni_)                       \
      acc[mi_][ni_] = __builtin_amdgcn_mfma_f32_16x16x32_f16(                 \
          af_[mi_], bf_[ni_], acc[mi_][ni_], 0, 0, 0);                        \
} while (0)

#define PIPELINE_LOOP(NT) do {                                                \
  STAGE4(q0); STAGE4(q1);                                                     \
  VMCNT(4); BARRIER();                                                        \
  for (int t = 0; t < (NT); ++t) {                                            \
    if (t + 2 < (NT)) { STAGE4(q2); }                                         \
    COMPUTE8(q0);                                                             \
    if (t + 2 < (NT)) { VMCNT(4); } else { VMCNT(0); }                        \
    BARRIER();                                                                \
    f16* tm_ = q0; q0 = q1; q1 = q2; q2 = tm_;                                \
  }                                                                           \
} while (0)

// =====================  GEMM1: h = relu(x @ W1 + b1)  =======================
__global__ __launch_bounds__(256, 3) void gemm1_kernel(
    const f16* __restrict__ x16, const f16* __restrict__ w1t,
    const float* __restrict__ bias1, const int* __restrict__ tok_list,
    const int* __restrict__ counts, const int* __restrict__ bases,
    const int* __restrict__ slot_e, const int* __restrict__ slot_m0,
    const int* __restrict__ slot_g, int c0, int G,
    f16* __restrict__ h16) {
  int sx = blockIdx.x;
  int e  = slot_e[sx];
  if (e < 0) return;
  int g  = slot_g[sx];
  if (g < c0 || g >= c0 + G) return;
  int m0 = slot_m0[sx];
  int cnt = counts[e], base = bases[e];
  int n0 = blockIdx.y * BN;
  const f16* Bg = w1t + (size_t)e * INNER * HID;

  __shared__ __align__(16) f16 LDS[3 * 8192];
  f16 *q0 = LDS, *q1 = LDS + 8192, *q2 = LDS + 2 * 8192;

  int tid = threadIdx.x, lane = tid & 63, wid = tid >> 6;
  int wm = (wid >> 1) * 64, wn = (wid & 1) * 64;
  int ar = lane & 15, hi = lane >> 4;
  int cswz = hi ^ ((ar >> 1) & 3);

  // staging: thread t -> rows (t>>2) and (t>>2)+64, stored chunk col t&3,
  // global chunk col pre-swizzled: (t&3) ^ ((row>>1)&3) = (t&3)^((t>>3)&3)
  int trow = tid >> 2;
  int gcol = (tid & 3) ^ ((tid >> 3) & 3);
  const f16* gA[2];
  const f16* gB[2];
#pragma unroll
  for (int i = 0; i < 2; ++i) {
    int row = i * 64 + trow;
    int tok = tok_list[base + min(m0 + row, cnt - 1)];
    gA[i] = x16 + (size_t)tok * HID + gcol * 8;
    gB[i] = Bg + (size_t)(n0 + row) * HID + gcol * 8;
  }

  f32x4 acc[4][4];
#pragma unroll
  for (int i = 0; i < 4; ++i)
#pragma unroll
    for (int j = 0; j < 4; ++j) acc[i][j] = (f32x4){0.f, 0.f, 0.f, 0.f};

  PIPELINE_LOOP(HID / BK);   // 32

  int colc = ar, rbase = hi * 4;
  float bb[4];
#pragma unroll
  for (int ni = 0; ni < 4; ++ni)
    bb[ni] = bias1[(size_t)e * INNER + n0 + wn + ni * 16 + colc];
#pragma unroll
  for (int mi = 0; mi < 4; ++mi)
#pragma unroll
    for (int r = 0; r < 4; ++r) {
      int ml = wm + mi * 16 + rbase + r;
      if (m0 + ml < cnt) {
        size_t rowoff = (size_t)((g - c0) * BM + ml) * INNER + n0 + wn + colc;
#pragma unroll
        for (int ni = 0; ni < 4; ++ni) {
          float v = acc[mi][ni][r] + bb[ni];
          h16[rowoff + ni * 16] = (f16)fmaxf(v, 0.f);
        }
      }
    }
}

// =====================  GEMM2: out += w * (h @ W2 + b2), K-split=2  =========
__global__ __launch_bounds__(256, 3) void gemm2_kernel(
    const f16* __restrict__ h16, const f16* __restrict__ w2t,
    const float* __restrict__ bias2, const int* __restrict__ tok_list,
    const float* __restrict__ wt_list, const int* __restrict__ counts,
    const int* __restrict__ bases,
    const int* __restrict__ slot_e, const int* __restrict__ slot_m0,
    const int* __restrict__ slot_g, int c0, int G,
    float* __restrict__ out) {
  int sx = blockIdx.x;
  int e  = slot_e[sx];
  if (e < 0) return;
  int g  = slot_g[sx];
  if (g < c0 || g >= c0 + G) return;
  int m0 = slot_m0[sx];
  int cnt = counts[e], base = bases[e];
  int d0 = blockIdx.y * BN;
  int kc = blockIdx.z;
  int koff = kc * (INNER / 2);
  const f16* Bg = w2t + (size_t)e * HID * INNER;

  __shared__ __align__(16) f16 LDS[3 * 8192];
  f16 *q0 = LDS, *q1 = LDS + 8192, *q2 = LDS + 2 * 8192;

  int tid = threadIdx.x, lane = tid & 63, wid = tid >> 6;
  int wm = (wid >> 1) * 64, wn = (wid & 1) * 64;
  int ar = lane & 15, hi = lane >> 4;
  int cswz = hi ^ ((ar >> 1) & 3);

  int trow = tid >> 2;
  int gcol = (tid & 3) ^ ((tid >> 3) & 3);
  const f16* gA[2];
  const f16* gB[2];
#pragma unroll
  for (int i = 0; i < 2; ++i) {
    int row  = i * 64 + trow;
    int lrow = min(m0 + row, cnt - 1) - m0;
    gA[i] = h16 + ((size_t)(g - c0) * BM + lrow) * INNER + koff + gcol * 8;
    gB[i] = Bg + (size_t)(d0 + row) * INNER + koff + gcol * 8;
  }

  f32x4 acc[4][4];
#pragma unroll
  for (int i = 0; i < 4; ++i)
#pragma unroll
    for (int j = 0; j < 4; ++j) acc[i][j] = (f32x4){0.f, 0.f, 0.f, 0.f};

  PIPELINE_LOOP((INNER / 2) / BK);   // 32

  int colc = ar, rbase = hi * 4;
  float bb[4];
#pragma unroll
  for (int ni = 0; ni < 4; ++ni)
    bb[ni] = (kc == 0) ? bias2[(size_t)e * HID + d0 + wn + ni * 16 + colc] : 0.f;
#pragma unroll
  for (int mi = 0; mi < 4; ++mi)
#pragma unroll
    for (int r = 0; r < 4; ++r) {
      int ml = wm + mi * 16 + rbase + r;
      if (m0 + ml < cnt) {
        int   p   = base + m0 + ml;
        int   tok = tok_list[p];
        float w   = wt_list[p];
        float* orow = out + (size_t)tok * HID + d0 + wn + colc;
#pragma unroll
        for (int ni = 0; ni < 4; ++ni) {
          float v = acc[mi][ni][r] + bb[ni];
          atomicAdd(orow + ni * 16, v * w);
        }
      }
    }
}

// ===========================================================================
extern "C" void kernel_launch(void* const* d_in, const int* in_sizes, int n_in,
                              void* d_out, int out_size, void* d_ws, size_t ws_size,
                              hipStream_t stream) {
  (void)in_sizes; (void)n_in;
  const float* x  = (const float*)d_in[0];
  const float* Wr = (const float*)d_in[1];
  const float* br = (const float*)d_in[2];
  const float* W1 = (const float*)d_in[3];
  const float* b1 = (const float*)d_in[4];
  const float* W2 = (const float*)d_in[5];
  const float* b2 = (const float*)d_in[6];
  float* out = (float*)d_out;

  char*  ws  = (char*)d_ws;
  size_t off = 0;
  auto alloc = [&](size_t bytes) {
    char* p = ws + off;
    off += bytes; off = (off + 255) & ~(size_t)255;
    return p;
  };
  int*   tok_list = (int*)alloc(NPAIR * sizeof(int));
  float* wt_list  = (float*)alloc(NPAIR * sizeof(float));
  int*   e_sel    = (int*)alloc(NTOK * 2 * sizeof(int));
  float* w_sel    = (float*)alloc(NTOK * 2 * sizeof(float));
  int*   counts   = (int*)alloc(EXPERTS * sizeof(int));
  int*   bases    = (int*)alloc(EXPERTS * sizeof(int));
  int*   slot_e   = (int*)alloc(NSLOT * sizeof(int));
  int*   slot_m0  = (int*)alloc(NSLOT * sizeof(int));
  int*   slot_g   = (int*)alloc(NSLOT * sizeof(int));
  int*   tinfo    = (int*)alloc(16 * sizeof(int));
  f16*   w1t      = (f16*)alloc((size_t)EXPERTS * HID * INNER * sizeof(f16));
  f16*   w2t      = (f16*)alloc((size_t)EXPERTS * HID * INNER * sizeof(f16));
  f16*   x16      = (f16*)alloc((size_t)NTOK * HID * sizeof(f16));
  const size_t TILE_BYTES = (size_t)BM * INNER * sizeof(f16);  // 512 KB
  size_t rem = (ws_size > off) ? (ws_size - off) : 0;
  int G = (int)(rem / TILE_BYTES);
  if (G < 1) G = 1;
  if (G > MAXT) G = MAXT;
  int nch = (MAXT + G - 1) / G;
  f16* h16 = (f16*)(ws + off);

  hipMemsetAsync(out, 0, (size_t)out_size * sizeof(float), stream);

  convert_x_kernel<<<2048, 256, 0, stream>>>(x, x16, NTOK * HID / 8);
  transpose_cvt_kernel<<<dim3(INNER / 32, HID / 32, EXPERTS), dim3(32, 8), 0, stream>>>(
      W1, w1t, HID, INNER);
  transpose_cvt_kernel<<<dim3(HID / 32, INNER / 32, EXPERTS), dim3(32, 8), 0, stream>>>(
      W2, w2t, INNER, HID);
  router_kernel<<<NTOK / 4, 256, 0, stream>>>(x, Wr, br, e_sel, w_sel);
  dispatch_kernel<<<1, 1024, 0, stream>>>(e_sel, w_sel, tok_list, wt_list,
                                          counts, bases, slot_e, slot_m0, slot_g, tinfo);

  for (int c = 0; c < nch; ++c) {
    int c0 = c * G;
    gemm1_kernel<<<dim3(NSLOT, INNER / BN, 1), 256, 0, stream>>>(
        x16, w1t, b1, tok_list, counts, bases, slot_e, slot_m0, slot_g, c0, G, h16);
    gemm2_kernel<<<dim3(NSLOT, HID / BN, 2), 256, 0, stream>>>(
        h16, w2t, b2, tok_list, wt_list, counts, bases, slot_e, slot_m0, slot_g, c0, G, out);
  }
}

// Round 12
// 485.147 us; speedup vs baseline: 1.0994x; 1.0362x over previous
//
#include <hip/hip_runtime.h>
#include <stdint.h>

#define HID    1024
#define EXPERTS 8
#define TOPK   2
#define INNER  2048
#define NTOK   8192            // B*S
#define NPAIR  (NTOK * TOPK)   // 16384
#define MAXT   72              // max expert-pure 256-row tiles: 16384/256 + 8
#define BM 256
#define BN 128
#define BK 32
#define AFFS  9                // affinity slots per expert (8*9 = 72 = MAXT)
#define NSLOT 144              // 72 affinity + 72 overflow (144 % 8 == 0)

typedef _Float16 f16;
typedef f16   f16x8 __attribute__((ext_vector_type(8)));
typedef float f32x4 __attribute__((ext_vector_type(4)));

#define VMCNT(n) asm volatile("s_waitcnt vmcnt(" #n ")" ::: "memory")
#define BARRIER() do { __builtin_amdgcn_s_barrier(); asm volatile("" ::: "memory"); } while (0)

__device__ __forceinline__ void gload_lds16(const void* g, void* l) {
  __builtin_amdgcn_global_load_lds(
      (const __attribute__((address_space(1))) void*)g,
      (__attribute__((address_space(3))) void*)l, 16, 0, 0);
}

// ==========  router: logits, top-2, softmax + fused x->fp16 convert  ========
__global__ void router_kernel(const float* __restrict__ x,
                              const float* __restrict__ Wr,
                              const float* __restrict__ br,
                              int* __restrict__ e_sel, float* __restrict__ w_sel,
                              f16* __restrict__ x16) {
  int gid  = blockIdx.x * blockDim.x + threadIdx.x;
  int wid  = gid >> 6;           // one wave per token
  int lane = gid & 63;
  if (wid >= NTOK) return;

  const f32x4* xr = (const f32x4*)(x + (size_t)wid * HID);
  f16* xw = x16 + (size_t)wid * HID;
  float acc[EXPERTS];
#pragma unroll
  for (int e = 0; e < EXPERTS; ++e) acc[e] = 0.f;
#pragma unroll
  for (int j = 0; j < HID / 256; ++j) {
    f32x4 xv = xr[j * 64 + lane];
    // fused fp32 -> fp16 store (8B per lane, coalesced per 64-lane group)
    union { f16 h[4]; double d; } cv;
#pragma unroll
    for (int r = 0; r < 4; ++r) cv.h[r] = (f16)xv[r];
    *(double*)(xw + (j * 64 + lane) * 4) = cv.d;

    int   k  = (j * 64 + lane) * 4;
    const float* wr = Wr + (size_t)k * EXPERTS;
#pragma unroll
    for (int r = 0; r < 4; ++r) {
      float xs = xv[r];
      f32x4 w0 = *(const f32x4*)(wr + r * 8);
      f32x4 w1 = *(const f32x4*)(wr + r * 8 + 4);
#pragma unroll
      for (int e = 0; e < 4; ++e) { acc[e] += xs * w0[e]; acc[4 + e] += xs * w1[e]; }
    }
  }
#pragma unroll
  for (int e = 0; e < EXPERTS; ++e) {
#pragma unroll
    for (int off = 32; off > 0; off >>= 1) acc[e] += __shfl_xor(acc[e], off);
  }
  if (lane == 0) {
    float lg[EXPERTS];
#pragma unroll
    for (int e = 0; e < EXPERTS; ++e) lg[e] = acc[e] + br[e];
    int e0 = 0; float l0 = lg[0];
#pragma unroll
    for (int e = 1; e < EXPERTS; ++e) if (lg[e] > l0) { l0 = lg[e]; e0 = e; }
    int e1 = -1; float l1 = -3.4e38f;
#pragma unroll
    for (int e = 0; e < EXPERTS; ++e) if (e != e0 && lg[e] > l1) { l1 = lg[e]; e1 = e; }
    float a  = __expf(l1 - l0);
    float w0 = 1.f / (1.f + a);
    float w1 = a * w0;
    e_sel[wid * 2]     = e0;  e_sel[wid * 2 + 1] = e1;
    w_sel[wid * 2]     = w0;  w_sel[wid * 2 + 1] = w1;
  }
}

// ====  dispatch: counts + scan + slot map (XCD affinity) + scatter  =========
__global__ __launch_bounds__(1024) void dispatch_kernel(
    const int* __restrict__ e_sel, const float* __restrict__ w_sel,
    int* __restrict__ tok_list, float* __restrict__ wt_list,
    int* __restrict__ counts, int* __restrict__ bases,
    int* __restrict__ slot_e, int* __restrict__ slot_m0,
    int* __restrict__ slot_g, int* __restrict__ tinfo) {
  __shared__ int scnt[EXPERTS][1024];
  __shared__ int etot[EXPERTS];
  __shared__ int ebase[EXPERTS];
  int tid = threadIdx.x, lane = tid & 63, wv = tid >> 6;

  int myE[16]; float myW[16];
  int lc[EXPERTS];
#pragma unroll
  for (int e = 0; e < EXPERTS; ++e) lc[e] = 0;
#pragma unroll
  for (int i = 0; i < 16; ++i) {
    int p = tid * 16 + i;
    myE[i] = e_sel[p];
    myW[i] = w_sel[p];
#pragma unroll
    for (int e = 0; e < EXPERTS; ++e) lc[e] += (myE[i] == e);
  }
#pragma unroll
  for (int e = 0; e < EXPERTS; ++e) scnt[e][tid] = lc[e];
  __syncthreads();

  if (wv < EXPERTS) {
    int run = 0;
    for (int c = 0; c < 16; ++c) {
      int v = scnt[wv][c * 64 + lane];
      int incl = v;
#pragma unroll
      for (int off = 1; off < 64; off <<= 1) {
        int n = __shfl_up(incl, off);
        if (lane >= off) incl += n;
      }
      scnt[wv][c * 64 + lane] = run + incl - v;
      run += __shfl(incl, 63);
    }
    if (lane == 0) etot[wv] = run;
  }
  __syncthreads();

  if (tid < NSLOT) slot_e[tid] = -1;
  __syncthreads();
  if (tid == 0) {
    int s = 0;
    for (int e = 0; e < EXPERTS; ++e) {
      ebase[e] = s; bases[e] = s; counts[e] = etot[e]; s += etot[e];
    }
    int ov = AFFS * EXPERTS, gt = 0;
    for (int e = 0; e < EXPERTS; ++e) {
      int ntl = (etot[e] + BM - 1) / BM;
      for (int i = 0; i < ntl; ++i) {
        int sl = (i < AFFS) ? (e + EXPERTS * i) : (ov++);
        slot_e[sl] = e; slot_m0[sl] = i * BM; slot_g[sl] = gt++;
      }
    }
    tinfo[0] = gt;
  }
  __syncthreads();

  int cur[EXPERTS];
#pragma unroll
  for (int e = 0; e < EXPERTS; ++e) cur[e] = ebase[e] + scnt[e][tid];
#pragma unroll
  for (int i = 0; i < 16; ++i) {
    int p = 0;
#pragma unroll
    for (int e = 0; e < EXPERTS; ++e) if (myE[i] == e) p = cur[e]++;
    tok_list[p] = (tid * 16 + i) >> 1;
    wt_list[p]  = myW[i];
  }
}

// =====================  pre-pass: weight transpose fp32->fp16  ==============
__global__ void transpose_cvt_kernel(const float* __restrict__ src,
                                     f16* __restrict__ dst, int R, int C) {
  __shared__ float tile[32][33];
  int z = blockIdx.z;
  src += (size_t)z * R * C;
  dst += (size_t)z * R * C;
  int c0 = blockIdx.x * 32, r0 = blockIdx.y * 32;
  int tx = threadIdx.x, ty = threadIdx.y;
#pragma unroll
  for (int i = 0; i < 4; ++i)
    tile[ty + i * 8][tx] = src[(size_t)(r0 + ty + i * 8) * C + c0 + tx];
  __syncthreads();
#pragma unroll
  for (int i = 0; i < 4; ++i)
    dst[(size_t)(c0 + ty + i * 8) * R + r0 + tx] = (f16)tile[tx][ty + i * 8];
}

// ============================================================================
// GEMM core: 256x128 tile, BK=32, 8 waves (4m x 2n of 64x64), counted-vmcnt
// depth-2-in-flight pipeline over 3 LDS buffers (24 KB each = 72 KB -> 2
// blocks/CU = 16 waves/CU).  Buffer: A[256 rows][64B] at f16 ofs 0, B[128
// rows][64B] at f16 ofs 8192.  Stored chunk (row,c) holds global chunk
// (row, c^((row>>1)&3)) via pre-swizzled GLOBAL source (lds dest linear).
// Per stage: 3 gload_lds / thread (2 A + 1 B); vmcnt(3) keeps one extra
// stage in flight across the single per-step barrier.
// Intensity: 128 MFMA (2.1 MFLOP) per 24 KB staged = 87 FLOP/B.
// ============================================================================

#define BUFSZ 12288  // f16 per buffer

#define STAGE3(BUF) do {                                                      \
  gload_lds16(gA[0], (BUF) + wid * 512);          gA[0] += BK;                \
  gload_lds16(gA[1], (BUF) + 4096 + wid * 512);   gA[1] += BK;                \
  gload_lds16(gB0,   (BUF) + 8192 + wid * 512);   gB0   += BK;                \
} while (0)

#define COMPUTE16(BUF) do {                                                   \
  f16x8 af_[4], bf_[4];                                                       \
  _Pragma("unroll") for (int mi_ = 0; mi_ < 4; ++mi_)                         \
    af_[mi_] = *(const f16x8*)((BUF) + (wm + mi_ * 16 + ar) * 32 + cswz * 8); \
  _Pragma("unroll") for (int ni_ = 0; ni_ < 4; ++ni_)                         \
    bf_[ni_] = *(const f16x8*)((BUF) + 8192 +                                 \
                               (wn + ni_ * 16 + ar) * 32 + cswz * 8);         \
  _Pragma("unroll") for (int mi_ = 0; mi_ < 4; ++mi_)                         \
    _Pragma("unroll") for (int ni_ = 0; ni_ < 4; ++ni_)                       \
      acc[mi_][ni_] = __builtin_amdgcn_mfma_f32_16x16x32_f16(                 \
          af_[mi_], bf_[ni_], acc[mi_][ni_], 0, 0, 0);                        \
} while (0)

#define PIPELINE_LOOP(NT) do {                                                \
  STAGE3(q0); STAGE3(q1);                                                     \
  VMCNT(3); BARRIER();                                                        \
  for (int t = 0; t < (NT); ++t) {                                            \
    if (t + 2 < (NT)) { STAGE3(q2); }                                         \
    COMPUTE16(q0);                                                            \
    if (t + 2 < (NT)) { VMCNT(3); } else { VMCNT(0); }                        \
    BARRIER();                                                                \
    f16* tm_ = q0; q0 = q1; q1 = q2; q2 = tm_;                                \
  }                                                                           \
} while (0)

// =====================  GEMM1: h = relu(x @ W1 + b1)  =======================
__global__ __launch_bounds__(512, 4) void gemm1_kernel(
    const f16* __restrict__ x16, const f16* __restrict__ w1t,
    const float* __restrict__ bias1, const int* __restrict__ tok_list,
    const int* __restrict__ counts, const int* __restrict__ bases,
    const int* __restrict__ slot_e, const int* __restrict__ slot_m0,
    const int* __restrict__ slot_g, int c0, int G,
    f16* __restrict__ h16) {
  int sx = blockIdx.x;
  int e  = slot_e[sx];
  if (e < 0) return;
  int g  = slot_g[sx];
  if (g < c0 || g >= c0 + G) return;
  int m0 = slot_m0[sx];
  int cnt = counts[e], base = bases[e];
  int n0 = blockIdx.y * BN;
  const f16* Bg = w1t + (size_t)e * INNER * HID;

  __shared__ __align__(16) f16 LDS[3 * BUFSZ];
  f16 *q0 = LDS, *q1 = LDS + BUFSZ, *q2 = LDS + 2 * BUFSZ;

  int tid = threadIdx.x, lane = tid & 63, wid = tid >> 6;
  int wm = (wid >> 1) * 64, wn = (wid & 1) * 64;
  int ar = lane & 15, hi = lane >> 4;
  int cswz = hi ^ ((ar >> 1) & 3);

  // staging map: A chunk c (c<512): row=c>>2, col=c&3; A chunk 512+c: row=128+(c>>2)
  // B chunk c: row=c>>2.  Source col pre-swizzled: (c&3)^((c>>3)&3) for all.
  int trow = tid >> 2;
  int gcol = (tid & 3) ^ ((tid >> 3) & 3);
  int tok0 = tok_list[base + min(m0 + trow, cnt - 1)];
  int tok1 = tok_list[base + min(m0 + 128 + trow, cnt - 1)];
  const f16* gA[2];
  gA[0] = x16 + (size_t)tok0 * HID + gcol * 8;
  gA[1] = x16 + (size_t)tok1 * HID + gcol * 8;
  const f16* gB0 = Bg + (size_t)(n0 + trow) * HID + gcol * 8;

  f32x4 acc[4][4];
#pragma unroll
  for (int i = 0; i < 4; ++i)
#pragma unroll
    for (int j = 0; j < 4; ++j) acc[i][j] = (f32x4){0.f, 0.f, 0.f, 0.f};

  PIPELINE_LOOP(HID / BK);   // 32

  int colc = ar, rbase = hi * 4;
  float bb[4];
#pragma unroll
  for (int ni = 0; ni < 4; ++ni)
    bb[ni] = bias1[(size_t)e * INNER + n0 + wn + ni * 16 + colc];
#pragma unroll
  for (int mi = 0; mi < 4; ++mi)
#pragma unroll
    for (int r = 0; r < 4; ++r) {
      int ml = wm + mi * 16 + rbase + r;
      if (m0 + ml < cnt) {
        size_t rowoff = (size_t)((g - c0) * BM + ml) * INNER + n0 + wn + colc;
#pragma unroll
        for (int ni = 0; ni < 4; ++ni) {
          float v = acc[mi][ni][r] + bb[ni];
          h16[rowoff + ni * 16] = (f16)fmaxf(v, 0.f);
        }
      }
    }
}

// =====================  GEMM2: out += w * (h @ W2 + b2)  ====================
__global__ __launch_bounds__(512, 4) void gemm2_kernel(
    const f16* __restrict__ h16, const f16* __restrict__ w2t,
    const float* __restrict__ bias2, const int* __restrict__ tok_list,
    const float* __restrict__ wt_list, const int* __restrict__ counts,
    const int* __restrict__ bases,
    const int* __restrict__ slot_e, const int* __restrict__ slot_m0,
    const int* __restrict__ slot_g, int c0, int G,
    float* __restrict__ out) {
  int sx = blockIdx.x;
  int e  = slot_e[sx];
  if (e < 0) return;
  int g  = slot_g[sx];
  if (g < c0 || g >= c0 + G) return;
  int m0 = slot_m0[sx];
  int cnt = counts[e], base = bases[e];
  int d0 = blockIdx.y * BN;
  const f16* Bg = w2t + (size_t)e * HID * INNER;

  __shared__ __align__(16) f16 LDS[3 * BUFSZ];
  f16 *q0 = LDS, *q1 = LDS + BUFSZ, *q2 = LDS + 2 * BUFSZ;

  int tid = threadIdx.x, lane = tid & 63, wid = tid >> 6;
  int wm = (wid >> 1) * 64, wn = (wid & 1) * 64;
  int ar = lane & 15, hi = lane >> 4;
  int cswz = hi ^ ((ar >> 1) & 3);

  int trow = tid >> 2;
  int gcol = (tid & 3) ^ ((tid >> 3) & 3);
  int lrow0 = min(m0 + trow, cnt - 1) - m0;
  int lrow1 = min(m0 + 128 + trow, cnt - 1) - m0;
  const f16* gA[2];
  gA[0] = h16 + ((size_t)(g - c0) * BM + lrow0) * INNER + gcol * 8;
  gA[1] = h16 + ((size_t)(g - c0) * BM + lrow1) * INNER + gcol * 8;
  const f16* gB0 = Bg + (size_t)(d0 + trow) * INNER + gcol * 8;

  f32x4 acc[4][4];
#pragma unroll
  for (int i = 0; i < 4; ++i)
#pragma unroll
    for (int j = 0; j < 4; ++j) acc[i][j] = (f32x4){0.f, 0.f, 0.f, 0.f};

  PIPELINE_LOOP(INNER / BK);   // 64

  int colc = ar, rbase = hi * 4;
  float bb[4];
#pragma unroll
  for (int ni = 0; ni < 4; ++ni)
    bb[ni] = bias2[(size_t)e * HID + d0 + wn + ni * 16 + colc];
#pragma unroll
  for (int mi = 0; mi < 4; ++mi)
#pragma unroll
    for (int r = 0; r < 4; ++r) {
      int ml = wm + mi * 16 + rbase + r;
      if (m0 + ml < cnt) {
        int   p   = base + m0 + ml;
        int   tok = tok_list[p];
        float w   = wt_list[p];
        float* orow = out + (size_t)tok * HID + d0 + wn + colc;
#pragma unroll
        for (int ni = 0; ni < 4; ++ni) {
          float v = acc[mi][ni][r] + bb[ni];
          atomicAdd(orow + ni * 16, v * w);
        }
      }
    }
}

// ===========================================================================
extern "C" void kernel_launch(void* const* d_in, const int* in_sizes, int n_in,
                              void* d_out, int out_size, void* d_ws, size_t ws_size,
                              hipStream_t stream) {
  (void)in_sizes; (void)n_in;
  const float* x  = (const float*)d_in[0];
  const float* Wr = (const float*)d_in[1];
  const float* br = (const float*)d_in[2];
  const float* W1 = (const float*)d_in[3];
  const float* b1 = (const float*)d_in[4];
  const float* W2 = (const float*)d_in[5];
  const float* b2 = (const float*)d_in[6];
  float* out = (float*)d_out;

  char*  ws  = (char*)d_ws;
  size_t off = 0;
  auto alloc = [&](size_t bytes) {
    char* p = ws + off;
    off += bytes; off = (off + 255) & ~(size_t)255;
    return p;
  };
  int*   tok_list = (int*)alloc(NPAIR * sizeof(int));
  float* wt_list  = (float*)alloc(NPAIR * sizeof(float));
  int*   e_sel    = (int*)alloc(NTOK * 2 * sizeof(int));
  float* w_sel    = (float*)alloc(NTOK * 2 * sizeof(float));
  int*   counts   = (int*)alloc(EXPERTS * sizeof(int));
  int*   bases    = (int*)alloc(EXPERTS * sizeof(int));
  int*   slot_e   = (int*)alloc(NSLOT * sizeof(int));
  int*   slot_m0  = (int*)alloc(NSLOT * sizeof(int));
  int*   slot_g   = (int*)alloc(NSLOT * sizeof(int));
  int*   tinfo    = (int*)alloc(16 * sizeof(int));
  f16*   w1t      = (f16*)alloc((size_t)EXPERTS * HID * INNER * sizeof(f16));
  f16*   w2t      = (f16*)alloc((size_t)EXPERTS * HID * INNER * sizeof(f16));
  f16*   x16      = (f16*)alloc((size_t)NTOK * HID * sizeof(f16));
  const size_t TILE_BYTES = (size_t)BM * INNER * sizeof(f16);  // 1 MB
  size_t rem = (ws_size > off) ? (ws_size - off) : 0;
  int G = (int)(rem / TILE_BYTES);
  if (G < 1) G = 1;
  if (G > MAXT) G = MAXT;
  int nch = (MAXT + G - 1) / G;
  f16* h16 = (f16*)(ws + off);

  hipMemsetAsync(out, 0, (size_t)out_size * sizeof(float), stream);

  router_kernel<<<NTOK / 4, 256, 0, stream>>>(x, Wr, br, e_sel, w_sel, x16);
  transpose_cvt_kernel<<<dim3(INNER / 32, HID / 32, EXPERTS), dim3(32, 8), 0, stream>>>(
      W1, w1t, HID, INNER);
  transpose_cvt_kernel<<<dim3(HID / 32, INNER / 32, EXPERTS), dim3(32, 8), 0, stream>>>(
      W2, w2t, INNER, HID);
  dispatch_kernel<<<1, 1024, 0, stream>>>(e_sel, w_sel, tok_list, wt_list,
                                          counts, bases, slot_e, slot_m0, slot_g, tinfo);

  for (int c = 0; c < nch; ++c) {
    int c0 = c * G;
    gemm1_kernel<<<dim3(NSLOT, INNER / BN, 1), 512, 0, stream>>>(
        x16, w1t, b1, tok_list, counts, bases, slot_e, slot_m0, slot_g, c0, G, h16);
    gemm2_kernel<<<dim3(NSLOT, HID / BN, 1), 512, 0, stream>>>(
        h16, w2t, b2, tok_list, wt_list, counts, bases, slot_e, slot_m0, slot_g, c0, G, out);
  }
}